// Round 6
// baseline (140.462 us; speedup 1.0000x reference)
//
#include <hip/hip_runtime.h>
#include <hip/hip_bf16.h>

#define HH 64
#define WW 64
#define CIN 128
#define COUT 256
#define KK 1152            // CIN*9
#define PW 66              // padded NHWC width/height
#define XTIMG (PW*PW*CIN)  // elems per padded image = 557568

typedef short bf16x8 __attribute__((ext_vector_type(8)));
typedef float f32x4  __attribute__((ext_vector_type(4)));

__device__ inline short f2bf(float f) {
    union { float f; unsigned u; } v; v.f = f;
    unsigned r = v.u + 0x7FFFu + ((v.u >> 16) & 1u);   // RNE
    return (short)(r >> 16);
}
__device__ inline float lo16(unsigned u) {
    union { unsigned u; float f; } v; v.u = u << 16; return v.f;
}
__device__ inline float hi16(unsigned u) {
    union { unsigned u; float f; } v; v.u = u & 0xffff0000u; return v.f;
}
__device__ inline unsigned pk2(float lo, float hi) {
    union { __hip_bfloat162 h; unsigned u; } c;
    c.h = __float22bfloat162_rn(make_float2(lo, hi));
    return c.u;
}

// ---- kernel 0: prep = NCHW->NHWC bf16 transpose (blocks 0..527) + weight casts (528..689)
__global__ __launch_bounds__(256) void prep(const float* __restrict__ x,
                                            const float* __restrict__ wd,
                                            const float* __restrict__ wo,
                                            ushort* __restrict__ xt,
                                            short* __restrict__ wf,
                                            short* __restrict__ wfo) {
    int bi = blockIdx.x, t = threadIdx.x;
    if (bi >= 528) {
        // weight cast to MFMA A-fragment order: element ((m*36+ks)*64+l)*8+j
        int flat = (bi - 528) * 256 + t;       // 0..41471 = 18 m * 36 ks * 64 l
        int m = flat / 2304;
        int r = flat - m * 2304;
        int ks = r >> 6, l = r & 63;
        bf16x8 v;
        if (m < 16) {
            int co = m * 16 + (l & 15);
#pragma unroll
            for (int j = 0; j < 8; j++) {
                int ckp = ks * 32 + ((l >> 4) << 3) + j;
                int c = ckp & 127, k = ckp >> 7;
                v[j] = f2bf(wd[(size_t)co * KK + c * 9 + k]);
            }
            *(bf16x8*)(wf + ((size_t)(m * 36 + ks) * 64 + l) * 8) = v;
        } else {
            int mm = m - 16;
            int co = mm * 16 + (l & 15);
#pragma unroll
            for (int j = 0; j < 8; j++) {
                int ckp = ks * 32 + ((l >> 4) << 3) + j;
                int c = ckp & 127, k = ckp >> 7;
                v[j] = (co < 18) ? f2bf(wo[(size_t)co * KK + c * 9 + k]) : (short)0;
            }
            *(bf16x8*)(wfo + ((size_t)(mm * 36 + ks) * 64 + l) * 8) = v;
        }
        return;
    }
    int hp = bi % 66, b = bi / 66;
    ushort* row = xt + ((size_t)b * PW + hp) * PW * CIN;   // 8448 elems
    if (hp == 0 || hp == PW - 1) {
        ushort4 z4 = {0, 0, 0, 0};
        for (int f = t; f < 2112; f += 256) ((ushort4*)row)[f] = z4;
        return;
    }
    __shared__ short tl[66 * 132];   // [wp][c], stride 132
    int h = hp - 1;
    if (t < 128) { tl[t] = 0; tl[65 * 132 + t] = 0; }
    const float* xbh = x + (((size_t)b * CIN) << 12) + (h << 6);
#pragma unroll
    for (int it = 0; it < 8; it++) {
        int c  = it * 16 + (t >> 4);
        int w4 = (t & 15) * 4;
        float4 v = *(const float4*)(xbh + ((size_t)c << 12) + w4);
        tl[(w4 + 1) * 132 + c] = f2bf(v.x);
        tl[(w4 + 2) * 132 + c] = f2bf(v.y);
        tl[(w4 + 3) * 132 + c] = f2bf(v.z);
        tl[(w4 + 4) * 132 + c] = f2bf(v.w);
    }
    __syncthreads();
    for (int f = t; f < 2112; f += 256) {      // 2112 ushort4 = 8448 elems
        int wp = f >> 5, c4 = (f & 31) * 4;
        const short* s = &tl[wp * 132 + c4];
        ushort4 v; v.x = s[0]; v.y = s[1]; v.z = s[2]; v.w = s[3];
        ((ushort4*)row)[f] = v;
    }
}

// ---- kernel 1: FUSED offset-conv (LDS-free MFMA) + in-register bilinear + deform MFMA
// grid 512: b=bi&7 (XCD pin), h=bi>>3. Block = whole row (64 px), 4 waves, M=64/wave.
__global__ __launch_bounds__(256, 2) void fused_deform(const ushort* __restrict__ xt,
                                                       const short* __restrict__ wf,
                                                       const short* __restrict__ wfo,
                                                       const float* __restrict__ bo,
                                                       const float* __restrict__ bias,
                                                       float* __restrict__ out) {
    __shared__ short   s_val[64][128];   // 16 KB: B-fragments, xor-swizzled granules
    __shared__ float4  s_w[9][64];       // bilinear weights (wy0a0,wy0a1,wy1a0,wy1a1)
    __shared__ ushort2 s_o[9][64];       // two row-base padded locations
    __shared__ float   s_off[18][64];    // phase-0 offsets

    int t = threadIdx.x, bi = blockIdx.x;
    int b = bi & 7, h = bi >> 3;
    const ushort* xb = xt + (size_t)b * XTIMG;
    int wv = t >> 6, l = t & 63, lane16 = l & 15, quad = l >> 4;

    // ========== phase 0: offset conv, zero LDS staging, zero barriers ==========
    {
        f32x4 aoff0 = {0.f, 0.f, 0.f, 0.f}, aoff1 = aoff0;
        const short* A0 = wfo + (size_t)l * 8;                // m-tile 0
        const short* A1 = wfo + (size_t)36 * 512 + l * 8;     // m-tile 1
        int pix0 = lane16 + 16 * wv;                          // n-tile = wv
#pragma unroll 1
        for (int k = 0; k < 9; k++) {
            const ushort* bbase = xb + ((size_t)(h + k / 3) * PW + pix0 + k % 3) * CIN + quad * 8;
#pragma unroll
            for (int ksp = 0; ksp < 4; ksp++) {
                int ks = k * 4 + ksp;
                bf16x8 bfr = *(const bf16x8*)(bbase + ksp * 32);
                bf16x8 af0 = *(const bf16x8*)(A0 + (size_t)ks * 512);
                bf16x8 af1 = *(const bf16x8*)(A1 + (size_t)ks * 512);
                aoff0 = __builtin_amdgcn_mfma_f32_16x16x32_bf16(af0, bfr, aoff0, 0, 0, 0);
                aoff1 = __builtin_amdgcn_mfma_f32_16x16x32_bf16(af1, bfr, aoff1, 0, 0, 0);
            }
        }
#pragma unroll
        for (int r = 0; r < 4; r++) {
            int co = quad * 4 + r;                            // 0..15, all < 18
            s_off[co][pix0] = aoff0[r] + bo[co];
            int co1 = co + 16;
            if (co1 < 18) s_off[co1][pix0] = aoff1[r] + bo[co1];
        }
    }
    __syncthreads();

    // ========== sampling params: 9 kernel points x 64 pixels ==========
    for (int jj = t; jj < 576; jj += 256) {
        int k = jj >> 6, pixj = jj & 63, wp = pixj;
        float dy = s_off[2 * k][pixj];
        float dx = s_off[2 * k + 1][pixj];
        float py = (float)(h + k / 3 - 1) + dy;
        float px = (float)(wp + k % 3 - 1) + dx;
        float y0f = floorf(py), x0f = floorf(px);
        float ly = py - y0f, lx = px - x0f;
        int y0 = (int)y0f, x0 = (int)x0f;
        float a0, a1;
        if (x0 >= 0 && x0 <= 62)      { a0 = 1.f - lx; a1 = lx; }
        else if (x0 == -1)            { a0 = lx;       a1 = 0.f; }
        else if (x0 == 63)            { a0 = 0.f;      a1 = 1.f - lx; }
        else                          { a0 = 0.f;      a1 = 0.f; }
        int xb0 = min(max(x0, 0), 62);
        bool vy0 = (y0 >= 0) && (y0 < HH);
        bool vy1 = (y0 >= -1) && (y0 < HH - 1);
        int y0c = min(max(y0, 0), HH - 1);
        int y1c = min(max(y0 + 1, 0), HH - 1);
        float wy0 = (1.f - ly) * (vy0 ? 1.f : 0.f);
        float wy1 = ly * (vy1 ? 1.f : 0.f);
        s_o[k][pixj] = make_ushort2((ushort)((y0c + 1) * PW + xb0 + 1),
                                    (ushort)((y1c + 1) * PW + xb0 + 1));
        s_w[k][pixj] = make_float4(wy0 * a0, wy0 * a1, wy1 * a0, wy1 * a1);
    }

    // ========== main loop: gather->bilinear in registers -> s_val -> MFMA ==========
    int gpix = t >> 2, sub = t & 3;                 // 4 lanes per pixel, 32 ch each
    const ushort* xg = xb + sub * 8;
    bf16x8 cur[4];                                  // packed B-frag granules for chunk k

    auto gli = [&](int k) {                         // load 16x16B (64B-coalesced) + bilinear
        ushort2 o = s_o[k][gpix];
        float4 w4 = s_w[k][gpix];
        const ushort* p0 = xg + (size_t)o.x * CIN;
        const ushort* p1 = xg + (size_t)o.y * CIN;
        uint4 c00[4], c01[4], c10[4], c11[4];
#pragma unroll
        for (int i = 0; i < 4; i++) {
            c00[i] = *(const uint4*)(p0 + i * 32);
            c01[i] = *(const uint4*)(p0 + 128 + i * 32);
            c10[i] = *(const uint4*)(p1 + i * 32);
            c11[i] = *(const uint4*)(p1 + 128 + i * 32);
        }
#pragma unroll
        for (int i = 0; i < 4; i++) {
            uint4 o4;
            const unsigned* u00 = (const unsigned*)&c00[i];
            const unsigned* u01 = (const unsigned*)&c01[i];
            const unsigned* u10 = (const unsigned*)&c10[i];
            const unsigned* u11 = (const unsigned*)&c11[i];
            unsigned* ov = (unsigned*)&o4;
#pragma unroll
            for (int d = 0; d < 4; d++) {
                float vl = w4.x * lo16(u00[d]) + w4.y * lo16(u01[d])
                         + w4.z * lo16(u10[d]) + w4.w * lo16(u11[d]);
                float vh = w4.x * hi16(u00[d]) + w4.y * hi16(u01[d])
                         + w4.z * hi16(u10[d]) + w4.w * hi16(u11[d]);
                ov[d] = pk2(vl, vh);
            }
            cur[i] = *(bf16x8*)&o4;
        }
    };

    f32x4 z = {0.f, 0.f, 0.f, 0.f};
    f32x4 acc[4][4];                                // [m-tile][n-tile]
#pragma unroll
    for (int i = 0; i < 4; i++)
#pragma unroll
        for (int j = 0; j < 4; j++) acc[i][j] = z;
    const short* Aw = wf + (size_t)l * 8;

    __syncthreads();                                // s_o/s_w ready
    gli(0);

    for (int k = 0; k < 9; k++) {
#pragma unroll
        for (int i = 0; i < 4; i++)                 // write B-frags, xor-swizzled
            *(bf16x8*)&s_val[gpix][((((i << 2) + sub) ^ (gpix & 15)) << 3)] = cur[i];
        __syncthreads();
        if (k < 8) gli(k + 1);                      // loads in flight during MFMA
#pragma unroll
        for (int ksp = 0; ksp < 4; ksp++) {
            int ks = k * 4 + ksp;
            int gg = (ksp << 2) + quad;
            bf16x8 b0 = *(const bf16x8*)&s_val[lane16     ][(gg ^ lane16) << 3];
            bf16x8 b1 = *(const bf16x8*)&s_val[16 + lane16][(gg ^ lane16) << 3];
            bf16x8 b2 = *(const bf16x8*)&s_val[32 + lane16][(gg ^ lane16) << 3];
            bf16x8 b3 = *(const bf16x8*)&s_val[48 + lane16][(gg ^ lane16) << 3];
#pragma unroll
            for (int mt = 0; mt < 4; mt++) {
                bf16x8 a = *(const bf16x8*)(Aw + (size_t)(((wv * 4 + mt) * 36) + ks) * 512);
                acc[mt][0] = __builtin_amdgcn_mfma_f32_16x16x32_bf16(a, b0, acc[mt][0], 0, 0, 0);
                acc[mt][1] = __builtin_amdgcn_mfma_f32_16x16x32_bf16(a, b1, acc[mt][1], 0, 0, 0);
                acc[mt][2] = __builtin_amdgcn_mfma_f32_16x16x32_bf16(a, b2, acc[mt][2], 0, 0, 0);
                acc[mt][3] = __builtin_amdgcn_mfma_f32_16x16x32_bf16(a, b3, acc[mt][3], 0, 0, 0);
            }
        }
        __syncthreads();
    }

    // ---- epilogue: bias + relu + store. D: col(pix)=lane16, row(co)=quad*4+r
#pragma unroll
    for (int mt = 0; mt < 4; mt++) {
        int co = (wv * 4 + mt) * 16 + quad * 4;
#pragma unroll
        for (int nt = 0; nt < 4; nt++) {
            int colx = nt * 16 + lane16;
#pragma unroll
            for (int rr = 0; rr < 4; rr++) {
                float v = acc[mt][nt][rr] + bias[co + rr];
                out[(((size_t)b * COUT + co + rr) << 12) + (h << 6) + colx] = fmaxf(v, 0.f);
            }
        }
    }
}

extern "C" void kernel_launch(void* const* d_in, const int* in_sizes, int n_in,
                              void* d_out, int out_size, void* d_ws, size_t ws_size,
                              hipStream_t stream) {
    const float* x     = (const float*)d_in[0];
    const float* w_off = (const float*)d_in[1];
    const float* b_off = (const float*)d_in[2];
    const float* w_def = (const float*)d_in[3];
    const float* b_def = (const float*)d_in[4];
    float* out = (float*)d_out;

    // ws: wf bf16 [16*36*512] | wfo bf16 [2*36*512] | xt bf16 [8*66*66*128]
    short*  wf  = (short*)d_ws;
    short*  wfo = wf + (size_t)16 * 36 * 512;
    ushort* xt  = (ushort*)(wfo + (size_t)2 * 36 * 512);

    prep<<<690, 256, 0, stream>>>(x, w_def, w_off, xt, wf, wfo);
    fused_deform<<<512, 256, 0, stream>>>(xt, wf, wfo, b_off, b_def, out);
}

// Round 7
// 134.975 us; speedup vs baseline: 1.0406x; 1.0406x over previous
//
#include <hip/hip_runtime.h>
#include <hip/hip_bf16.h>

#define HH 64
#define WW 64
#define CIN 128
#define COUT 256
#define KK 1152            // CIN*9
#define PW 66              // padded NHWC width/height
#define XTIMG (PW*PW*CIN)  // elems per padded image = 557568

typedef short bf16x8 __attribute__((ext_vector_type(8)));
typedef float f32x4  __attribute__((ext_vector_type(4)));

__device__ inline short f2bf(float f) {
    union { float f; unsigned u; } v; v.f = f;
    unsigned r = v.u + 0x7FFFu + ((v.u >> 16) & 1u);   // RNE
    return (short)(r >> 16);
}
__device__ inline float lo16(unsigned u) {
    union { unsigned u; float f; } v; v.u = u << 16; return v.f;
}
__device__ inline float hi16(unsigned u) {
    union { unsigned u; float f; } v; v.u = u & 0xffff0000u; return v.f;
}
__device__ inline unsigned pk2(float lo, float hi) {
    union { __hip_bfloat162 h; unsigned u; } c;
    c.h = __float22bfloat162_rn(make_float2(lo, hi));
    return c.u;
}

// ---- kernel 0: prep. blocks 0..527: NCHW f32 -> NHWC bf16 padded transpose (LDS-free).
//                blocks 528..689: weight casts to MFMA A-fragment order.
__global__ __launch_bounds__(256) void prep(const float* __restrict__ x,
                                            const float* __restrict__ wd,
                                            const float* __restrict__ wo,
                                            ushort* __restrict__ xt,
                                            short* __restrict__ wf,
                                            short* __restrict__ wfo) {
    int bi = blockIdx.x, t = threadIdx.x;
    if (bi < 528) {
        int b = bi & 7, hp = bi >> 3;                    // XCD-pinned by image
        ushort* row = xt + ((size_t)b * PW + hp) * PW * CIN;   // 8448 elems
        if (hp == 0 || hp == 65) {
            uint4 z = {0, 0, 0, 0};
            for (int f = t; f < 1056; f += 256) ((uint4*)row)[f] = z;
            return;
        }
        int h = hp - 1;
        int w = t & 63, c0 = (t >> 6) * 32;
        const float* xs = x + (((size_t)b * CIN + c0) << 12) + (h << 6) + w;
        float v[32];
#pragma unroll
        for (int i = 0; i < 32; i++) v[i] = xs[(size_t)i << 12];   // coalesced dwords
        unsigned dw[16];
#pragma unroll
        for (int i = 0; i < 16; i++) dw[i] = pk2(v[2 * i], v[2 * i + 1]);
        ushort* dst = row + ((w + 1) * 128 + c0);
#pragma unroll
        for (int i = 0; i < 4; i++) *(uint4*)(dst + i * 8) = *(uint4*)&dw[i * 4];
        if (t < 32) {                                    // zero border cols w=0,65
            uint4 z = {0, 0, 0, 0};
            int px = (t >> 4) * 65;
            *(uint4*)(row + px * 128 + (t & 15) * 8) = z;
        }
        return;
    }
    // ---- weight cast: element ((m*36+ks)*64+l)*8+j, ck' = ks*32+(l>>4)*8+j, c=ck'&127, k=ck'>>7
    int flat = (bi - 528) * 256 + t;       // 0..41471 = 18 m * 36 ks * 64 l
    int m = flat / 2304;
    int r = flat - m * 2304;
    int ks = r >> 6, l = r & 63;
    bf16x8 v8;
    if (m < 16) {
        int co = m * 16 + (l & 15);
#pragma unroll
        for (int j = 0; j < 8; j++) {
            int ckp = ks * 32 + ((l >> 4) << 3) + j;
            int c = ckp & 127, k = ckp >> 7;
            v8[j] = f2bf(wd[(size_t)co * KK + c * 9 + k]);
        }
        *(bf16x8*)(wf + ((size_t)(m * 36 + ks) * 64 + l) * 8) = v8;
    } else {
        int mm = m - 16;
        int co = mm * 16 + (l & 15);
#pragma unroll
        for (int j = 0; j < 8; j++) {
            int ckp = ks * 32 + ((l >> 4) << 3) + j;
            int c = ckp & 127, k = ckp >> 7;
            v8[j] = (co < 18) ? f2bf(wo[(size_t)co * KK + c * 9 + k]) : (short)0;
        }
        *(bf16x8*)(wfo + ((size_t)(mm * 36 + ks) * 64 + l) * 8) = v8;
    }
}

// ---- kernel 1: FUSED offset-conv + sampling + deform MFMA. 512 threads = 8 waves.
// grid 512: b=bi&7 (XCD pin), h=bi>>3. Wave wv owns co 32*wv..32*wv+31 (2 m-tiles x 4 n-tiles).
__global__ __launch_bounds__(512, 4) void fused_deform(const ushort* __restrict__ xt,
                                                       const short* __restrict__ wf,
                                                       const short* __restrict__ wfo,
                                                       const float* __restrict__ bo,
                                                       const float* __restrict__ bias,
                                                       float* __restrict__ out) {
    __shared__ short   s_val[2][64][128];  // 32 KB dbuf B-fragments, xor-swizzled granules
    __shared__ float4  s_w[9][64];         // bilinear weights (clamp/validity folded)
    __shared__ ushort2 s_o[9][64];         // two padded row-base locations
    __shared__ float   s_off[18][64];      // phase-0 offsets

    int t = threadIdx.x, bi = blockIdx.x;
    int b = bi & 7, h = bi >> 3;
    const ushort* xb = xt + (size_t)b * XTIMG;
    int wv = t >> 6, l = t & 63, lane16 = l & 15, quad = l >> 4;

    // ========== phase 0: offset conv (M=32 pad of 18, K=1152), LDS-free ==========
    {
        int mt = wv >> 2, nt = wv & 3;
        int pix0 = nt * 16 + lane16;
        f32x4 aoff = {0.f, 0.f, 0.f, 0.f};
        const short* A = wfo + (size_t)mt * 36 * 512 + l * 8;
#pragma unroll
        for (int k = 0; k < 9; k++) {
            const ushort* bbase = xb + ((size_t)(h + k / 3) * PW + pix0 + k % 3) * CIN + quad * 8;
#pragma unroll
            for (int ksp = 0; ksp < 4; ksp++) {
                bf16x8 bfr = *(const bf16x8*)(bbase + ksp * 32);
                bf16x8 afr = *(const bf16x8*)(A + (k * 4 + ksp) * 512);
                aoff = __builtin_amdgcn_mfma_f32_16x16x32_bf16(afr, bfr, aoff, 0, 0, 0);
            }
        }
#pragma unroll
        for (int r = 0; r < 4; r++) {
            int co = mt * 16 + quad * 4 + r;
            if (co < 18) s_off[co][pix0] = aoff[r] + bo[co];
        }
    }
    __syncthreads();

    // ========== sampling params: 9 kernel points x 64 pixels ==========
    for (int jj = t; jj < 576; jj += 512) {
        int k = jj >> 6, pixj = jj & 63;
        float dy = s_off[2 * k][pixj];
        float dx = s_off[2 * k + 1][pixj];
        float py = (float)(h + k / 3 - 1) + dy;
        float px = (float)(pixj + k % 3 - 1) + dx;
        float y0f = floorf(py), x0f = floorf(px);
        float ly = py - y0f, lx = px - x0f;
        int y0 = (int)y0f, x0 = (int)x0f;
        float a0, a1;
        if (x0 >= 0 && x0 <= 62)      { a0 = 1.f - lx; a1 = lx; }
        else if (x0 == -1)            { a0 = lx;       a1 = 0.f; }
        else if (x0 == 63)            { a0 = 0.f;      a1 = 1.f - lx; }
        else                          { a0 = 0.f;      a1 = 0.f; }
        int xb0 = min(max(x0, 0), 62);
        bool vy0 = (y0 >= 0) && (y0 < HH);
        bool vy1 = (y0 >= -1) && (y0 < HH - 1);
        int y0c = min(max(y0, 0), HH - 1);
        int y1c = min(max(y0 + 1, 0), HH - 1);
        float wy0 = (1.f - ly) * (vy0 ? 1.f : 0.f);
        float wy1 = ly * (vy1 ? 1.f : 0.f);
        s_o[k][pixj] = make_ushort2((ushort)((y0c + 1) * PW + xb0 + 1),
                                    (ushort)((y1c + 1) * PW + xb0 + 1));
        s_w[k][pixj] = make_float4(wy0 * a0, wy0 * a1, wy1 * a0, wy1 * a1);
    }

    // ========== main loop: load(k+1) -> MFMA(k) -> bilinear+store(k+1) -> barrier ==========
    int p = t >> 3, j = t & 7, c0 = j * 16;        // 8 threads/pixel, 16 ch each
    int g0 = ((2 * j) ^ (p & 15)) * 8, g1 = ((2 * j + 1) ^ (p & 15)) * 8;
    bf16x8 rv[8];
    auto gload = [&](int k) {                      // 8x b128, 4 bilinear corners x 16 ch
        ushort2 o = s_o[k][p];
        const ushort* p0 = xb + (size_t)o.x * CIN + c0;
        const ushort* p1 = xb + (size_t)o.y * CIN + c0;
        rv[0] = *(const bf16x8*)(p0);       rv[1] = *(const bf16x8*)(p0 + 8);
        rv[2] = *(const bf16x8*)(p0 + 128); rv[3] = *(const bf16x8*)(p0 + 136);
        rv[4] = *(const bf16x8*)(p1);       rv[5] = *(const bf16x8*)(p1 + 8);
        rv[6] = *(const bf16x8*)(p1 + 128); rv[7] = *(const bf16x8*)(p1 + 136);
    };
    auto gstore = [&](int k, int buf) {            // bilinear in registers, 2 granule stores
        float4 w4 = s_w[k][p];
        unsigned oa[4], ob[4];
        const unsigned* u0 = (const unsigned*)&rv[0];
        const unsigned* u2 = (const unsigned*)&rv[2];
        const unsigned* u4 = (const unsigned*)&rv[4];
        const unsigned* u6 = (const unsigned*)&rv[6];
        const unsigned* u1 = (const unsigned*)&rv[1];
        const unsigned* u3 = (const unsigned*)&rv[3];
        const unsigned* u5 = (const unsigned*)&rv[5];
        const unsigned* u7 = (const unsigned*)&rv[7];
#pragma unroll
        for (int d = 0; d < 4; d++) {
            float vl = w4.x * lo16(u0[d]) + w4.y * lo16(u2[d]) + w4.z * lo16(u4[d]) + w4.w * lo16(u6[d]);
            float vh = w4.x * hi16(u0[d]) + w4.y * hi16(u2[d]) + w4.z * hi16(u4[d]) + w4.w * hi16(u6[d]);
            oa[d] = pk2(vl, vh);
            float wl = w4.x * lo16(u1[d]) + w4.y * lo16(u3[d]) + w4.z * lo16(u5[d]) + w4.w * lo16(u7[d]);
            float wh = w4.x * hi16(u1[d]) + w4.y * hi16(u3[d]) + w4.z * hi16(u5[d]) + w4.w * hi16(u7[d]);
            ob[d] = pk2(wl, wh);
        }
        *(bf16x8*)&s_val[buf][p][g0] = *(bf16x8*)oa;
        *(bf16x8*)&s_val[buf][p][g1] = *(bf16x8*)ob;
    };

    f32x4 z = {0.f, 0.f, 0.f, 0.f};
    f32x4 acc[2][4];
#pragma unroll
    for (int i = 0; i < 2; i++)
#pragma unroll
        for (int jj2 = 0; jj2 < 4; jj2++) acc[i][jj2] = z;
    const short* Aw = wf + (size_t)l * 8 + (size_t)(wv * 2) * 36 * 512;

    __syncthreads();                               // s_o/s_w ready
    gload(0); gstore(0, 0);
    __syncthreads();

    for (int k = 0; k < 9; k++) {
        if (k < 8) gload(k + 1);                   // loads in flight across MFMA(k)
#pragma unroll
        for (int ksp = 0; ksp < 4; ksp++) {
            int ks = k * 4 + ksp;
            int gsw = ((ksp * 4 + quad) ^ lane16) * 8;
            bf16x8 b0 = *(const bf16x8*)&s_val[k & 1][lane16     ][gsw];
            bf16x8 b1 = *(const bf16x8*)&s_val[k & 1][16 + lane16][gsw];
            bf16x8 b2 = *(const bf16x8*)&s_val[k & 1][32 + lane16][gsw];
            bf16x8 b3 = *(const bf16x8*)&s_val[k & 1][48 + lane16][gsw];
            bf16x8 a0 = *(const bf16x8*)(Aw + (size_t)(0 * 36 + ks) * 512);
            bf16x8 a1 = *(const bf16x8*)(Aw + (size_t)(1 * 36 + ks) * 512);
            acc[0][0] = __builtin_amdgcn_mfma_f32_16x16x32_bf16(a0, b0, acc[0][0], 0, 0, 0);
            acc[0][1] = __builtin_amdgcn_mfma_f32_16x16x32_bf16(a0, b1, acc[0][1], 0, 0, 0);
            acc[0][2] = __builtin_amdgcn_mfma_f32_16x16x32_bf16(a0, b2, acc[0][2], 0, 0, 0);
            acc[0][3] = __builtin_amdgcn_mfma_f32_16x16x32_bf16(a0, b3, acc[0][3], 0, 0, 0);
            acc[1][0] = __builtin_amdgcn_mfma_f32_16x16x32_bf16(a1, b0, acc[1][0], 0, 0, 0);
            acc[1][1] = __builtin_amdgcn_mfma_f32_16x16x32_bf16(a1, b1, acc[1][1], 0, 0, 0);
            acc[1][2] = __builtin_amdgcn_mfma_f32_16x16x32_bf16(a1, b2, acc[1][2], 0, 0, 0);
            acc[1][3] = __builtin_amdgcn_mfma_f32_16x16x32_bf16(a1, b3, acc[1][3], 0, 0, 0);
        }
        if (k < 8) gstore(k + 1, (k + 1) & 1);     // write other buffer
        __syncthreads();                           // single barrier per chunk
    }

    // ---- epilogue: bias + relu + store. D: col(pix)=lane16, row(co)=quad*4+r
#pragma unroll
    for (int mt2 = 0; mt2 < 2; mt2++) {
        int co = (wv * 2 + mt2) * 16 + quad * 4;
#pragma unroll
        for (int nt = 0; nt < 4; nt++) {
            int colx = nt * 16 + lane16;
#pragma unroll
            for (int rr = 0; rr < 4; rr++) {
                float v = acc[mt2][nt][rr] + bias[co + rr];
                out[(((size_t)b * COUT + co + rr) << 12) + (h << 6) + colx] = fmaxf(v, 0.f);
            }
        }
    }
}

extern "C" void kernel_launch(void* const* d_in, const int* in_sizes, int n_in,
                              void* d_out, int out_size, void* d_ws, size_t ws_size,
                              hipStream_t stream) {
    const float* x     = (const float*)d_in[0];
    const float* w_off = (const float*)d_in[1];
    const float* b_off = (const float*)d_in[2];
    const float* w_def = (const float*)d_in[3];
    const float* b_def = (const float*)d_in[4];
    float* out = (float*)d_out;

    // ws: wf bf16 [16*36*512] | wfo bf16 [2*36*512] | xt bf16 [8*66*66*128]
    short*  wf  = (short*)d_ws;
    short*  wfo = wf + (size_t)16 * 36 * 512;
    ushort* xt  = (ushort*)(wfo + (size_t)2 * 36 * 512);

    prep<<<690, 256, 0, stream>>>(x, w_def, w_off, xt, wf, wfo);
    fused_deform<<<512, 512, 0, stream>>>(xt, wf, wfo, b_off, b_def, out);
}